// Round 6
// baseline (458.827 us; speedup 1.0000x reference)
//
#include <hip/hip_runtime.h>
#include <hip/hip_bf16.h>
#include <math.h>

#define D      128
#define NID    16
#define H      4
#define CH     32
#define NLAYER 4
#define EPS    1e-5f
#define NEG    0.2f

typedef __attribute__((ext_vector_type(8))) short short8;
typedef __attribute__((ext_vector_type(4))) float floatx4;

__device__ __forceinline__ float2 bf2_to_f2(unsigned int u) {
    float2 r;
    unsigned int lo = u << 16;
    unsigned int hi = u & 0xffff0000u;
    r.x = __uint_as_float(lo);
    r.y = __uint_as_float(hi);
    return r;
}

__device__ __forceinline__ unsigned short f2bf(float f) {
    __hip_bfloat16 h = __float2bfloat16(f);
    return *reinterpret_cast<unsigned short*>(&h);
}

// ---------------------------------------------------------------------------
// CSR build pieces
// ---------------------------------------------------------------------------

__global__ __launch_bounds__(256) void count_deg_kernel(const int* __restrict__ dst, int e, int* deg) {
    int i = blockIdx.x * blockDim.x + threadIdx.x;
    if (i < e) atomicAdd(&deg[dst[i]], 1);
}

__global__ __launch_bounds__(256) void scan_blocks_kernel(const int* __restrict__ deg, int* __restrict__ offs,
                                                          int* __restrict__ bsum, int n) {
    __shared__ int sw[8];
    int t = threadIdx.x;
    int i = blockIdx.x * 256 + t;
    int v = (i < n) ? deg[i] : 0;
    int lane = t & 63, w = t >> 6;
    int x = v;
    #pragma unroll
    for (int off = 1; off < 64; off <<= 1) {
        int y = __shfl_up(x, off, 64);
        if (lane >= off) x += y;
    }
    if (lane == 63) sw[w] = x;
    __syncthreads();
    if (t == 0) {
        int s = 0;
        for (int k = 0; k < 4; ++k) { int tv = sw[k]; sw[k] = s; s += tv; }
        sw[4] = s;
    }
    __syncthreads();
    int excl = x - v + sw[w];
    if (i < n) offs[i] = excl;
    if (t == 255) bsum[blockIdx.x] = sw[4];
}

__global__ __launch_bounds__(256) void scan_bsum_kernel(int* bsum, int nb) {
    __shared__ int sw[8];
    int t = threadIdx.x;
    int v = (t < nb) ? bsum[t] : 0;
    int lane = t & 63, w = t >> 6;
    int x = v;
    #pragma unroll
    for (int off = 1; off < 64; off <<= 1) {
        int y = __shfl_up(x, off, 64);
        if (lane >= off) x += y;
    }
    if (lane == 63) sw[w] = x;
    __syncthreads();
    if (t == 0) {
        int s = 0;
        for (int k = 0; k < 4; ++k) { int tv = sw[k]; sw[k] = s; s += tv; }
    }
    __syncthreads();
    int excl = x - v + sw[w];
    if (t < nb) bsum[t] = excl;
}

__global__ __launch_bounds__(256) void add_offsets_kernel(int* __restrict__ offs, const int* __restrict__ bsum,
                                                          int* __restrict__ cursor, int n, int total) {
    int i = blockIdx.x * blockDim.x + threadIdx.x;
    if (i < n) {
        int o = offs[i] + bsum[i >> 8];
        offs[i] = o;
        cursor[i] = o;
    }
    if (i == 0) offs[n] = total;
}

__global__ __launch_bounds__(256) void scatter_kernel(const int* __restrict__ src, const int* __restrict__ dst,
                                                      int e, int n, int* cursor, int* __restrict__ csr_src) {
    int i = blockIdx.x * blockDim.x + threadIdx.x;
    if (i < e) {
        int pos = atomicAdd(&cursor[dst[i]], 1);
        csr_src[pos] = src[i];
    } else if (i < e + n) {
        int node = i - e;
        int pos = atomicAdd(&cursor[node], 1);
        csr_src[pos] = node;  // self loop
    }
}

// ---------------------------------------------------------------------------
// Fused setup: [0,nbEmbed) embed+proj+LN+ReLU -> bf16 x;
// [nbEmbed, +512) W->bf16 W^T; [then] deg init.
// ---------------------------------------------------------------------------
__global__ __launch_bounds__(256) void setup_kernel(
    const int* __restrict__ types, const float* __restrict__ emb,
    const float* __restrict__ W, const float* __restrict__ b,
    const float* __restrict__ g, const float* __restrict__ beta,
    unsigned short* __restrict__ x,
    const float* __restrict__ Wl, const float* __restrict__ Wr,
    unsigned short* __restrict__ wt, int* __restrict__ deg,
    int n, int nbEmbed) {
    __shared__ float sW[NID * D];
    __shared__ float semb[3 * NID];
    int blk = blockIdx.x;
    int t = threadIdx.x;
    if (blk < nbEmbed) {
        for (int i = t; i < NID * D; i += 256) sW[i] = W[i];
        for (int i = t; i < 3 * NID; i += 256) semb[i] = emb[i];
        __syncthreads();
        int lane = t & 63, w = t >> 6;
        int node = blk * 4 + w;
        if (node >= n) return;
        int c0 = 2 * lane;
        int ty = types[node];
        const float* e = &semb[ty * NID];
        float v0 = b[c0], v1 = b[c0 + 1];
        #pragma unroll
        for (int k = 0; k < NID; ++k) {
            float ek = e[k];
            v0 = fmaf(ek, sW[k * D + c0], v0);
            v1 = fmaf(ek, sW[k * D + c0 + 1], v1);
        }
        float s = v0 + v1, sq = v0 * v0 + v1 * v1;
        #pragma unroll
        for (int off = 1; off < 64; off <<= 1) {
            s  += __shfl_xor(s, off, 64);
            sq += __shfl_xor(sq, off, 64);
        }
        float mu  = s * (1.0f / D);
        float var = sq * (1.0f / D) - mu * mu;
        float r   = rsqrtf(var + EPS);
        v0 = fmaxf((v0 - mu) * r * g[c0]     + beta[c0],     0.0f);
        v1 = fmaxf((v1 - mu) * r * g[c0 + 1] + beta[c0 + 1], 0.0f);
        unsigned int packed = (unsigned int)f2bf(v0) | ((unsigned int)f2bf(v1) << 16);
        *(unsigned int*)(x + (size_t)node * D + c0) = packed;
    } else if (blk < nbEmbed + 512) {
        int idx = (blk - nbEmbed) * 256 + t;   // L*2*D*D = 131072
        int k    = idx & (D - 1);
        int nrow = (idx >> 7) & (D - 1);
        int s    = (idx >> 14) & 1;
        int l    = idx >> 15;
        const float* Wm = s ? Wr : Wl;
        wt[idx] = f2bf(Wm[(size_t)l * D * D + (size_t)k * D + nrow]);
    } else {
        int i = (blk - nbEmbed - 512) * 256 + t;
        if (i < n) deg[i] = 1;  // self loop
    }
}

// ---------------------------------------------------------------------------
// Dual GEMM via bf16 MFMA; bf16 in (direct LDS copy), bf16 out via LDS.
// ---------------------------------------------------------------------------
__global__ __launch_bounds__(256) void dual_gemm_mfma_kernel(
    const unsigned short* __restrict__ x, const unsigned short* __restrict__ wt,
    const float* __restrict__ bl, const float* __restrict__ br,
    unsigned short* __restrict__ xl, unsigned short* __restrict__ xr, int n) {
    __shared__ __align__(16) unsigned short sa[64 * 136];
    int t = threadIdx.x;
    int nbase = blockIdx.x * 64;
    int rows = n - nbase; if (rows > 64) rows = 64;
    // ---- stage bf16 x -> LDS (stride 136) ----
    {
        int r   = t >> 2;
        int seg = t & 3;                 // 32 ch = 64 B each
        uint4* drow = (uint4*)(sa + r * 136 + seg * 32);
        if (r < rows) {
            const uint4* srow = (const uint4*)(x + (size_t)(nbase + r) * D + seg * 32);
            drow[0] = srow[0]; drow[1] = srow[1]; drow[2] = srow[2]; drow[3] = srow[3];
        } else {
            uint4 z = make_uint4(0, 0, 0, 0);
            drow[0] = z; drow[1] = z; drow[2] = z; drow[3] = z;
        }
    }
    __syncthreads();
    int lane = t & 63, w = t >> 6;
    int L = lane & 15, q = lane >> 4;
    int s  = w >> 1;          // 0: Wl, 1: Wr
    int n0 = (w & 1) * 64;    // col strip base within this matrix
    const unsigned short* wb = wt + ((size_t)s * D + n0) * D;
    floatx4 acc[4][4];
    #pragma unroll
    for (int mi = 0; mi < 4; ++mi)
        #pragma unroll
        for (int ni = 0; ni < 4; ++ni)
            acc[mi][ni] = (floatx4){0.0f, 0.0f, 0.0f, 0.0f};
    #pragma unroll
    for (int kk = 0; kk < 4; ++kk) {
        int ko = kk * 32 + q * 8;
        short8 a[4], b[4];
        #pragma unroll
        for (int mi = 0; mi < 4; ++mi)
            a[mi] = *(const short8*)(sa + (mi * 16 + L) * 136 + ko);
        #pragma unroll
        for (int ni = 0; ni < 4; ++ni)
            b[ni] = *(const short8*)(wb + (size_t)(ni * 16 + L) * D + ko);
        #pragma unroll
        for (int mi = 0; mi < 4; ++mi)
            #pragma unroll
            for (int ni = 0; ni < 4; ++ni)
                acc[mi][ni] = __builtin_amdgcn_mfma_f32_16x16x32_bf16(a[mi], b[ni], acc[mi][ni], 0, 0, 0);
    }
    // ---- epilogue via LDS: +bias, bf16, vectorized stores ----
    const float* bias = s ? br : bl;
    #pragma unroll 1
    for (int pass = 0; pass < 2; ++pass) {
        __syncthreads();
        if (s == pass) {
            #pragma unroll
            for (int ni = 0; ni < 4; ++ni) {
                int col = n0 + ni * 16 + L;
                float bv = bias[col];
                #pragma unroll
                for (int mi = 0; mi < 4; ++mi) {
                    #pragma unroll
                    for (int r = 0; r < 4; ++r) {
                        int row = mi * 16 + q * 4 + r;
                        sa[row * 136 + col] = f2bf(acc[mi][ni][r] + bv);
                    }
                }
            }
        }
        __syncthreads();
        unsigned short* outp = pass ? xr : xl;
        #pragma unroll
        for (int c = 0; c < 4; ++c) {
            int chunk = c * 256 + t;        // 0..1023
            int row   = chunk >> 4;
            int off   = (chunk & 15) * 8;
            if (row < rows) {
                short8 v = *(const short8*)(sa + row * 136 + off);
                *(short8*)(outp + (size_t)(nbase + row) * D + off) = v;
            }
        }
    }
}

// ---------------------------------------------------------------------------
// Fused GATv2 aggregation, 4-deep pipelined gathers. Wave = 1 node;
// lane = (edge slot g = lane>>4) x (channel block l = lane&15, 8 ch).
// 16 edges per loop iteration: 4 index loads + 4 uint4 gathers in flight.
// ---------------------------------------------------------------------------
__device__ __forceinline__ void gat_edge(uint4 u, bool valid,
                                         const float* __restrict__ xr8,
                                         const float* __restrict__ at8,
                                         float* __restrict__ acc, float& lsum) {
    float xv[8];
    {
        float2 a = bf2_to_f2(u.x), b = bf2_to_f2(u.y), c = bf2_to_f2(u.z), d = bf2_to_f2(u.w);
        xv[0]=a.x; xv[1]=a.y; xv[2]=b.x; xv[3]=b.y; xv[4]=c.x; xv[5]=c.y; xv[6]=d.x; xv[7]=d.y;
    }
    float p = 0.0f;
    #pragma unroll
    for (int i = 0; i < 8; ++i) {
        float e = xv[i] + xr8[i];
        e = fmaxf(e, NEG * e);          // leaky_relu, 0<NEG<1
        p = fmaf(at8[i], e, p);
    }
    p += __shfl_xor(p, 1, 64);          // reduce over the head's 4 lanes
    p += __shfl_xor(p, 2, 64);
    float wgt = valid ? __expf(p) : 0.0f;
    lsum += wgt;
    #pragma unroll
    for (int i = 0; i < 8; ++i) acc[i] = fmaf(wgt, xv[i], acc[i]);
}

__global__ __launch_bounds__(256) void gat_agg_kernel(
    const unsigned short* __restrict__ xl, const unsigned short* __restrict__ xr,
    const unsigned short* __restrict__ xin,
    const int* __restrict__ offs, const int* __restrict__ csr_src,
    const float* __restrict__ att,
    const float* __restrict__ gbias,
    const float* __restrict__ lng, const float* __restrict__ lnb,
    unsigned short* __restrict__ xout_bf, float* __restrict__ xout_f32, int n) {
    int t = threadIdx.x;
    int lane = t & 63, w = t >> 6;
    int node = blockIdx.x * 4 + w;
    if (node >= n) return;
    int g  = lane >> 4;
    int l  = lane & 15;
    int cb = l * 8;
    float xr8[8], at8[8];
    {
        uint4 u = *(const uint4*)(xr + (size_t)node * D + cb);
        float2 a = bf2_to_f2(u.x), b = bf2_to_f2(u.y), c = bf2_to_f2(u.z), d = bf2_to_f2(u.w);
        xr8[0]=a.x; xr8[1]=a.y; xr8[2]=b.x; xr8[3]=b.y; xr8[4]=c.x; xr8[5]=c.y; xr8[6]=d.x; xr8[7]=d.y;
        float4 t0 = *(const float4*)(att + cb);
        float4 t1 = *(const float4*)(att + cb + 4);
        at8[0]=t0.x; at8[1]=t0.y; at8[2]=t0.z; at8[3]=t0.w; at8[4]=t1.x; at8[5]=t1.y; at8[6]=t1.z; at8[7]=t1.w;
    }
    float acc[8];
    #pragma unroll
    for (int i = 0; i < 8; ++i) acc[i] = 0.0f;
    float lsum = 0.0f;
    int s0 = offs[node], s1 = offs[node + 1];
    for (int j = s0; j < s1; j += 16) {
        int j0 = j + g, j1 = j + 4 + g, j2 = j + 8 + g, j3 = j + 12 + g;
        bool v0 = j0 < s1, v1 = j1 < s1, v2 = j2 < s1, v3 = j3 < s1;
        int a0 = csr_src[v0 ? j0 : s0];
        int a1 = csr_src[v1 ? j1 : s0];
        int a2 = csr_src[v2 ? j2 : s0];
        int a3 = csr_src[v3 ? j3 : s0];
        uint4 u0 = *(const uint4*)(xl + (size_t)a0 * D + cb);
        uint4 u1 = *(const uint4*)(xl + (size_t)a1 * D + cb);
        uint4 u2 = *(const uint4*)(xl + (size_t)a2 * D + cb);
        uint4 u3 = *(const uint4*)(xl + (size_t)a3 * D + cb);
        gat_edge(u0, v0, xr8, at8, acc, lsum);
        gat_edge(u1, v1, xr8, at8, acc, lsum);
        gat_edge(u2, v2, xr8, at8, acc, lsum);
        gat_edge(u3, v3, xr8, at8, acc, lsum);
    }
    // cross-group reduction (sum over the 4 edge slots)
    #pragma unroll
    for (int i = 0; i < 8; ++i) {
        acc[i] += __shfl_xor(acc[i], 16, 64);
        acc[i] += __shfl_xor(acc[i], 32, 64);
    }
    lsum += __shfl_xor(lsum, 16, 64);
    lsum += __shfl_xor(lsum, 32, 64);
    float inv = 1.0f / lsum;
    // bias + residual (bf16)
    float xi[8];
    {
        uint4 u = *(const uint4*)(xin + (size_t)node * D + cb);
        float2 a = bf2_to_f2(u.x), b = bf2_to_f2(u.y), c = bf2_to_f2(u.z), d = bf2_to_f2(u.w);
        xi[0]=a.x; xi[1]=a.y; xi[2]=b.x; xi[3]=b.y; xi[4]=c.x; xi[5]=c.y; xi[6]=d.x; xi[7]=d.y;
    }
    float4 gb0 = *(const float4*)(gbias + cb);
    float4 gb1 = *(const float4*)(gbias + cb + 4);
    float gb[8] = {gb0.x, gb0.y, gb0.z, gb0.w, gb1.x, gb1.y, gb1.z, gb1.w};
    float v[8];
    #pragma unroll
    for (int i = 0; i < 8; ++i) v[i] = fmaf(acc[i], inv, gb[i] + xi[i]);
    // LayerNorm over the 16 channel-block lanes
    float s = 0.0f, sq = 0.0f;
    #pragma unroll
    for (int i = 0; i < 8; ++i) { s += v[i]; sq = fmaf(v[i], v[i], sq); }
    #pragma unroll
    for (int off = 1; off < 16; off <<= 1) {
        s  += __shfl_xor(s, off, 64);
        sq += __shfl_xor(sq, off, 64);
    }
    float mu  = s * (1.0f / D);
    float var = sq * (1.0f / D) - mu * mu;
    float r   = rsqrtf(var + EPS);
    float4 lg0 = *(const float4*)(lng + cb);
    float4 lg1 = *(const float4*)(lng + cb + 4);
    float4 lb0 = *(const float4*)(lnb + cb);
    float4 lb1 = *(const float4*)(lnb + cb + 4);
    float lg[8] = {lg0.x, lg0.y, lg0.z, lg0.w, lg1.x, lg1.y, lg1.z, lg1.w};
    float lb[8] = {lb0.x, lb0.y, lb0.z, lb0.w, lb1.x, lb1.y, lb1.z, lb1.w};
    float o[8];
    #pragma unroll
    for (int i = 0; i < 8; ++i) o[i] = fmaxf((v[i] - mu) * r * lg[i] + lb[i], 0.0f);
    if (g == 0) {
        if (xout_f32) {
            *(float4*)(xout_f32 + (size_t)node * D + cb)     = make_float4(o[0], o[1], o[2], o[3]);
            *(float4*)(xout_f32 + (size_t)node * D + cb + 4) = make_float4(o[4], o[5], o[6], o[7]);
        } else {
            unsigned int p0 = (unsigned int)f2bf(o[0]) | ((unsigned int)f2bf(o[1]) << 16);
            unsigned int p1 = (unsigned int)f2bf(o[2]) | ((unsigned int)f2bf(o[3]) << 16);
            unsigned int p2 = (unsigned int)f2bf(o[4]) | ((unsigned int)f2bf(o[5]) << 16);
            unsigned int p3 = (unsigned int)f2bf(o[6]) | ((unsigned int)f2bf(o[7]) << 16);
            *(uint4*)(xout_bf + (size_t)node * D + cb) = make_uint4(p0, p1, p2, p3);
        }
    }
}

// ---------------------------------------------------------------------------
extern "C" void kernel_launch(void* const* d_in, const int* in_sizes, int n_in,
                              void* d_out, int out_size, void* d_ws, size_t ws_size,
                              hipStream_t stream) {
    const int*   node_types = (const int*)d_in[0];
    const int*   edge_index = (const int*)d_in[1];
    const float* emb        = (const float*)d_in[2];
    const float* projW      = (const float*)d_in[3];
    const float* projb      = (const float*)d_in[4];
    const float* projg      = (const float*)d_in[5];
    const float* projbeta   = (const float*)d_in[6];
    const float* Wl         = (const float*)d_in[7];
    const float* bl         = (const float*)d_in[8];
    const float* Wr         = (const float*)d_in[9];
    const float* br         = (const float*)d_in[10];
    const float* att        = (const float*)d_in[11];
    const float* gbias      = (const float*)d_in[12];
    const float* lng        = (const float*)d_in[13];
    const float* lnb        = (const float*)d_in[14];
    float* out = (float*)d_out;

    int n = in_sizes[0];
    int e = in_sizes[1] / 2;
    const int* srcs = edge_index;
    const int* dsts = edge_index + e;

    char* p = (char*)d_ws;
    auto carve = [&](size_t bytes) {
        char* q = p;
        p += (bytes + 255) & ~(size_t)255;
        return q;
    };
    int*   deg     = (int*)carve((size_t)n * 4);
    int*   offs    = (int*)carve((size_t)(n + 1) * 4);
    int*   cursor  = (int*)carve((size_t)n * 4);
    int*   bsum    = (int*)carve(256 * 4);
    int*   csr_src = (int*)carve((size_t)(e + n) * 4);
    unsigned short* xbuf = (unsigned short*)carve((size_t)n * D * 2);
    unsigned short* xlb  = (unsigned short*)carve((size_t)n * D * 2);
    unsigned short* xrb  = (unsigned short*)carve((size_t)n * D * 2);
    unsigned short* wt   = (unsigned short*)carve((size_t)NLAYER * 2 * D * D * 2);

    int nb = (n + 255) / 256;        // 196 for N=50000
    int nbEmbed = (n + 3) / 4;       // 12500

    // ---- fused setup: embed/proj/LN -> bf16 x ; W -> bf16 W^T ; deg=1 ----
    setup_kernel<<<nbEmbed + 512 + nb, 256, 0, stream>>>(
        node_types, emb, projW, projb, projg, projbeta, xbuf,
        Wl, Wr, wt, deg, n, nbEmbed);

    // ---- CSR build (dst-sorted, self loops included) ----
    count_deg_kernel<<<(e + 255) / 256, 256, 0, stream>>>(dsts, e, deg);
    scan_blocks_kernel<<<nb, 256, 0, stream>>>(deg, offs, bsum, n);
    scan_bsum_kernel<<<1, 256, 0, stream>>>(bsum, nb);
    add_offsets_kernel<<<(n + 255) / 256, 256, 0, stream>>>(offs, bsum, cursor, n, e + n);
    scatter_kernel<<<(e + n + 255) / 256, 256, 0, stream>>>(srcs, dsts, e, n, cursor, csr_src);

    // ---- 4 GATv2 layers ----
    for (int layer = 0; layer < NLAYER; ++layer) {
        dual_gemm_mfma_kernel<<<(n + 63) / 64, 256, 0, stream>>>(
            xbuf, wt + (size_t)layer * 2 * D * D,
            bl + (size_t)layer * D, br + (size_t)layer * D, xlb, xrb, n);
        bool last = (layer == NLAYER - 1);
        gat_agg_kernel<<<(n + 3) / 4, 256, 0, stream>>>(
            xlb, xrb, xbuf, offs, csr_src,
            att + (size_t)layer * H * CH, gbias + (size_t)layer * D,
            lng + (size_t)layer * D, lnb + (size_t)layer * D,
            last ? (unsigned short*)nullptr : xbuf, last ? out : (float*)nullptr, n);
    }
}

// Round 7
// 443.446 us; speedup vs baseline: 1.0347x; 1.0347x over previous
//
#include <hip/hip_runtime.h>
#include <hip/hip_bf16.h>
#include <math.h>

#define D      128
#define NID    16
#define H      4
#define CH     32
#define NLAYER 4
#define EPS    1e-5f
#define NEG    0.2f

typedef __attribute__((ext_vector_type(8))) short short8;
typedef __attribute__((ext_vector_type(4))) float floatx4;

__device__ __forceinline__ float2 bf2_to_f2(unsigned int u) {
    float2 r;
    unsigned int lo = u << 16;
    unsigned int hi = u & 0xffff0000u;
    r.x = __uint_as_float(lo);
    r.y = __uint_as_float(hi);
    return r;
}

__device__ __forceinline__ unsigned short f2bf(float f) {
    __hip_bfloat16 h = __float2bfloat16(f);
    return *reinterpret_cast<unsigned short*>(&h);
}

// ---------------------------------------------------------------------------
// CSR build pieces
// ---------------------------------------------------------------------------

__global__ __launch_bounds__(256) void count_deg_kernel(const int* __restrict__ dst, int e, int* deg) {
    int i = blockIdx.x * blockDim.x + threadIdx.x;
    if (i < e) atomicAdd(&deg[dst[i]], 1);
}

__global__ __launch_bounds__(256) void scan_blocks_kernel(const int* __restrict__ deg, int* __restrict__ offs,
                                                          int* __restrict__ bsum, int n) {
    __shared__ int sw[8];
    int t = threadIdx.x;
    int i = blockIdx.x * 256 + t;
    int v = (i < n) ? deg[i] : 0;
    int lane = t & 63, w = t >> 6;
    int x = v;
    #pragma unroll
    for (int off = 1; off < 64; off <<= 1) {
        int y = __shfl_up(x, off, 64);
        if (lane >= off) x += y;
    }
    if (lane == 63) sw[w] = x;
    __syncthreads();
    if (t == 0) {
        int s = 0;
        for (int k = 0; k < 4; ++k) { int tv = sw[k]; sw[k] = s; s += tv; }
        sw[4] = s;
    }
    __syncthreads();
    int excl = x - v + sw[w];
    if (i < n) offs[i] = excl;
    if (t == 255) bsum[blockIdx.x] = sw[4];
}

__global__ __launch_bounds__(256) void scan_bsum_kernel(int* bsum, int nb) {
    __shared__ int sw[8];
    int t = threadIdx.x;
    int v = (t < nb) ? bsum[t] : 0;
    int lane = t & 63, w = t >> 6;
    int x = v;
    #pragma unroll
    for (int off = 1; off < 64; off <<= 1) {
        int y = __shfl_up(x, off, 64);
        if (lane >= off) x += y;
    }
    if (lane == 63) sw[w] = x;
    __syncthreads();
    if (t == 0) {
        int s = 0;
        for (int k = 0; k < 4; ++k) { int tv = sw[k]; sw[k] = s; s += tv; }
    }
    __syncthreads();
    int excl = x - v + sw[w];
    if (t < nb) bsum[t] = excl;
}

__global__ __launch_bounds__(256) void add_offsets_kernel(int* __restrict__ offs, const int* __restrict__ bsum,
                                                          int* __restrict__ cursor, int n, int total) {
    int i = blockIdx.x * blockDim.x + threadIdx.x;
    if (i < n) {
        int o = offs[i] + bsum[i >> 8];
        offs[i] = o;
        cursor[i] = o;
    }
    if (i == 0) offs[n] = total;
}

__global__ __launch_bounds__(256) void scatter_kernel(const int* __restrict__ src, const int* __restrict__ dst,
                                                      int e, int n, int* cursor, int* __restrict__ csr_src) {
    int i = blockIdx.x * blockDim.x + threadIdx.x;
    if (i < e) {
        int pos = atomicAdd(&cursor[dst[i]], 1);
        csr_src[pos] = src[i];
    } else if (i < e + n) {
        int node = i - e;
        int pos = atomicAdd(&cursor[node], 1);
        csr_src[pos] = node;  // self loop
    }
}

// ---------------------------------------------------------------------------
// Fused setup: [0,nbEmbed) embed+proj+LN+ReLU -> bf16 x;
// [nbEmbed, +512) W->bf16 W^T; [then] deg init.
// ---------------------------------------------------------------------------
__global__ __launch_bounds__(256) void setup_kernel(
    const int* __restrict__ types, const float* __restrict__ emb,
    const float* __restrict__ W, const float* __restrict__ b,
    const float* __restrict__ g, const float* __restrict__ beta,
    unsigned short* __restrict__ x,
    const float* __restrict__ Wl, const float* __restrict__ Wr,
    unsigned short* __restrict__ wt, int* __restrict__ deg,
    int n, int nbEmbed) {
    __shared__ float sW[NID * D];
    __shared__ float semb[3 * NID];
    int blk = blockIdx.x;
    int t = threadIdx.x;
    if (blk < nbEmbed) {
        for (int i = t; i < NID * D; i += 256) sW[i] = W[i];
        for (int i = t; i < 3 * NID; i += 256) semb[i] = emb[i];
        __syncthreads();
        int lane = t & 63, w = t >> 6;
        int node = blk * 4 + w;
        if (node >= n) return;
        int c0 = 2 * lane;
        int ty = types[node];
        const float* e = &semb[ty * NID];
        float v0 = b[c0], v1 = b[c0 + 1];
        #pragma unroll
        for (int k = 0; k < NID; ++k) {
            float ek = e[k];
            v0 = fmaf(ek, sW[k * D + c0], v0);
            v1 = fmaf(ek, sW[k * D + c0 + 1], v1);
        }
        float s = v0 + v1, sq = v0 * v0 + v1 * v1;
        #pragma unroll
        for (int off = 1; off < 64; off <<= 1) {
            s  += __shfl_xor(s, off, 64);
            sq += __shfl_xor(sq, off, 64);
        }
        float mu  = s * (1.0f / D);
        float var = sq * (1.0f / D) - mu * mu;
        float r   = rsqrtf(var + EPS);
        v0 = fmaxf((v0 - mu) * r * g[c0]     + beta[c0],     0.0f);
        v1 = fmaxf((v1 - mu) * r * g[c0 + 1] + beta[c0 + 1], 0.0f);
        unsigned int packed = (unsigned int)f2bf(v0) | ((unsigned int)f2bf(v1) << 16);
        *(unsigned int*)(x + (size_t)node * D + c0) = packed;
    } else if (blk < nbEmbed + 512) {
        int idx = (blk - nbEmbed) * 256 + t;   // L*2*D*D = 131072
        int k    = idx & (D - 1);
        int nrow = (idx >> 7) & (D - 1);
        int s    = (idx >> 14) & 1;
        int l    = idx >> 15;
        const float* Wm = s ? Wr : Wl;
        wt[idx] = f2bf(Wm[(size_t)l * D * D + (size_t)k * D + nrow]);
    } else {
        int i = (blk - nbEmbed - 512) * 256 + t;
        if (i < n) deg[i] = 1;  // self loop
    }
}

// ---------------------------------------------------------------------------
// Dual GEMM via bf16 MFMA; bf16 in/out. All 16 B-fragments preloaded into
// registers at entry (before staging+barrier) so the K-loop is pure LDS+MFMA.
// ---------------------------------------------------------------------------
__global__ __launch_bounds__(256) void dual_gemm_mfma_kernel(
    const unsigned short* __restrict__ x, const unsigned short* __restrict__ wt,
    const float* __restrict__ bl, const float* __restrict__ br,
    unsigned short* __restrict__ xl, unsigned short* __restrict__ xr, int n) {
    __shared__ __align__(16) unsigned short sa[64 * 136];
    int t = threadIdx.x;
    int nbase = blockIdx.x * 64;
    int rows = n - nbase; if (rows > 64) rows = 64;
    int lane = t & 63, w = t >> 6;
    int L = lane & 15, q = lane >> 4;
    int s  = w >> 1;          // 0: Wl, 1: Wr
    int n0 = (w & 1) * 64;    // col strip base within this matrix
    const unsigned short* wb = wt + ((size_t)s * D + n0) * D;
    // ---- preload all B fragments (independent L2 loads, overlap staging) ----
    short8 b[4][4];           // [kk][ni]
    #pragma unroll
    for (int kk = 0; kk < 4; ++kk)
        #pragma unroll
        for (int ni = 0; ni < 4; ++ni)
            b[kk][ni] = *(const short8*)(wb + (size_t)(ni * 16 + L) * D + kk * 32 + q * 8);
    // ---- stage bf16 x -> LDS (stride 136) ----
    {
        int r   = t >> 2;
        int seg = t & 3;                 // 32 ch = 64 B each
        uint4* drow = (uint4*)(sa + r * 136 + seg * 32);
        if (r < rows) {
            const uint4* srow = (const uint4*)(x + (size_t)(nbase + r) * D + seg * 32);
            drow[0] = srow[0]; drow[1] = srow[1]; drow[2] = srow[2]; drow[3] = srow[3];
        } else {
            uint4 z = make_uint4(0, 0, 0, 0);
            drow[0] = z; drow[1] = z; drow[2] = z; drow[3] = z;
        }
    }
    __syncthreads();
    floatx4 acc[4][4];
    #pragma unroll
    for (int mi = 0; mi < 4; ++mi)
        #pragma unroll
        for (int ni = 0; ni < 4; ++ni)
            acc[mi][ni] = (floatx4){0.0f, 0.0f, 0.0f, 0.0f};
    #pragma unroll
    for (int kk = 0; kk < 4; ++kk) {
        int ko = kk * 32 + q * 8;
        short8 a[4];
        #pragma unroll
        for (int mi = 0; mi < 4; ++mi)
            a[mi] = *(const short8*)(sa + (mi * 16 + L) * 136 + ko);
        #pragma unroll
        for (int mi = 0; mi < 4; ++mi)
            #pragma unroll
            for (int ni = 0; ni < 4; ++ni)
                acc[mi][ni] = __builtin_amdgcn_mfma_f32_16x16x32_bf16(a[mi], b[kk][ni], acc[mi][ni], 0, 0, 0);
    }
    // ---- epilogue via LDS: +bias, bf16, vectorized stores ----
    const float* bias = s ? br : bl;
    #pragma unroll 1
    for (int pass = 0; pass < 2; ++pass) {
        __syncthreads();
        if (s == pass) {
            #pragma unroll
            for (int ni = 0; ni < 4; ++ni) {
                int col = n0 + ni * 16 + L;
                float bv = bias[col];
                #pragma unroll
                for (int mi = 0; mi < 4; ++mi) {
                    #pragma unroll
                    for (int r = 0; r < 4; ++r) {
                        int row = mi * 16 + q * 4 + r;
                        sa[row * 136 + col] = f2bf(acc[mi][ni][r] + bv);
                    }
                }
            }
        }
        __syncthreads();
        unsigned short* outp = pass ? xr : xl;
        #pragma unroll
        for (int c = 0; c < 4; ++c) {
            int chunk = c * 256 + t;        // 0..1023
            int row   = chunk >> 4;
            int off   = (chunk & 15) * 8;
            if (row < rows) {
                short8 v = *(const short8*)(sa + row * 136 + off);
                *(short8*)(outp + (size_t)(nbase + row) * D + off) = v;
            }
        }
    }
}

// ---------------------------------------------------------------------------
// Fused GATv2 aggregation (R5-proven loop structure: one gather in flight,
// j += 4). Wave = 1 node; lane = (edge slot g = lane>>4) x (channel block
// l = lane&15, 8 ch each). bf16 gathers/residual; fp32 out on last layer.
// ---------------------------------------------------------------------------
__global__ __launch_bounds__(256) void gat_agg_kernel(
    const unsigned short* __restrict__ xl, const unsigned short* __restrict__ xr,
    const unsigned short* __restrict__ xin,
    const int* __restrict__ offs, const int* __restrict__ csr_src,
    const float* __restrict__ att,
    const float* __restrict__ gbias,
    const float* __restrict__ lng, const float* __restrict__ lnb,
    unsigned short* __restrict__ xout_bf, float* __restrict__ xout_f32, int n) {
    int t = threadIdx.x;
    int lane = t & 63, w = t >> 6;
    int node = blockIdx.x * 4 + w;
    if (node >= n) return;
    int g  = lane >> 4;
    int l  = lane & 15;
    int cb = l * 8;
    float xr8[8], at8[8];
    {
        uint4 u = *(const uint4*)(xr + (size_t)node * D + cb);
        float2 a = bf2_to_f2(u.x), b = bf2_to_f2(u.y), c = bf2_to_f2(u.z), d = bf2_to_f2(u.w);
        xr8[0]=a.x; xr8[1]=a.y; xr8[2]=b.x; xr8[3]=b.y; xr8[4]=c.x; xr8[5]=c.y; xr8[6]=d.x; xr8[7]=d.y;
        float4 t0 = *(const float4*)(att + cb);
        float4 t1 = *(const float4*)(att + cb + 4);
        at8[0]=t0.x; at8[1]=t0.y; at8[2]=t0.z; at8[3]=t0.w; at8[4]=t1.x; at8[5]=t1.y; at8[6]=t1.z; at8[7]=t1.w;
    }
    float acc[8];
    #pragma unroll
    for (int i = 0; i < 8; ++i) acc[i] = 0.0f;
    float lsum = 0.0f;
    int s0 = offs[node], s1 = offs[node + 1];
    for (int j = s0; j < s1; j += 4) {
        int je = j + g;
        bool valid = je < s1;
        int jc = valid ? je : s0;
        int src = csr_src[jc];
        uint4 u = *(const uint4*)(xl + (size_t)src * D + cb);
        float xv[8];
        {
            float2 a = bf2_to_f2(u.x), b = bf2_to_f2(u.y), c = bf2_to_f2(u.z), d = bf2_to_f2(u.w);
            xv[0]=a.x; xv[1]=a.y; xv[2]=b.x; xv[3]=b.y; xv[4]=c.x; xv[5]=c.y; xv[6]=d.x; xv[7]=d.y;
        }
        float p = 0.0f;
        #pragma unroll
        for (int i = 0; i < 8; ++i) {
            float e = xv[i] + xr8[i];
            e = fmaxf(e, NEG * e);      // leaky_relu, 0<NEG<1
            p = fmaf(at8[i], e, p);
        }
        p += __shfl_xor(p, 1, 64);      // reduce over the head's 4 lanes
        p += __shfl_xor(p, 2, 64);
        float wgt = valid ? __expf(p) : 0.0f;
        lsum += wgt;
        #pragma unroll
        for (int i = 0; i < 8; ++i) acc[i] = fmaf(wgt, xv[i], acc[i]);
    }
    // cross-group reduction (sum over the 4 edge slots)
    #pragma unroll
    for (int i = 0; i < 8; ++i) {
        acc[i] += __shfl_xor(acc[i], 16, 64);
        acc[i] += __shfl_xor(acc[i], 32, 64);
    }
    lsum += __shfl_xor(lsum, 16, 64);
    lsum += __shfl_xor(lsum, 32, 64);
    float inv = 1.0f / lsum;
    // bias + residual (bf16)
    float xi[8];
    {
        uint4 u = *(const uint4*)(xin + (size_t)node * D + cb);
        float2 a = bf2_to_f2(u.x), b = bf2_to_f2(u.y), c = bf2_to_f2(u.z), d = bf2_to_f2(u.w);
        xi[0]=a.x; xi[1]=a.y; xi[2]=b.x; xi[3]=b.y; xi[4]=c.x; xi[5]=c.y; xi[6]=d.x; xi[7]=d.y;
    }
    float4 gb0 = *(const float4*)(gbias + cb);
    float4 gb1 = *(const float4*)(gbias + cb + 4);
    float gb[8] = {gb0.x, gb0.y, gb0.z, gb0.w, gb1.x, gb1.y, gb1.z, gb1.w};
    float v[8];
    #pragma unroll
    for (int i = 0; i < 8; ++i) v[i] = fmaf(acc[i], inv, gb[i] + xi[i]);
    // LayerNorm over the 16 channel-block lanes
    float s = 0.0f, sq = 0.0f;
    #pragma unroll
    for (int i = 0; i < 8; ++i) { s += v[i]; sq = fmaf(v[i], v[i], sq); }
    #pragma unroll
    for (int off = 1; off < 16; off <<= 1) {
        s  += __shfl_xor(s, off, 64);
        sq += __shfl_xor(sq, off, 64);
    }
    float mu  = s * (1.0f / D);
    float var = sq * (1.0f / D) - mu * mu;
    float r   = rsqrtf(var + EPS);
    float4 lg0 = *(const float4*)(lng + cb);
    float4 lg1 = *(const float4*)(lng + cb + 4);
    float4 lb0 = *(const float4*)(lnb + cb);
    float4 lb1 = *(const float4*)(lnb + cb + 4);
    float lg[8] = {lg0.x, lg0.y, lg0.z, lg0.w, lg1.x, lg1.y, lg1.z, lg1.w};
    float lb[8] = {lb0.x, lb0.y, lb0.z, lb0.w, lb1.x, lb1.y, lb1.z, lb1.w};
    float o[8];
    #pragma unroll
    for (int i = 0; i < 8; ++i) o[i] = fmaxf((v[i] - mu) * r * lg[i] + lb[i], 0.0f);
    if (g == 0) {
        if (xout_f32) {
            *(float4*)(xout_f32 + (size_t)node * D + cb)     = make_float4(o[0], o[1], o[2], o[3]);
            *(float4*)(xout_f32 + (size_t)node * D + cb + 4) = make_float4(o[4], o[5], o[6], o[7]);
        } else {
            unsigned int p0 = (unsigned int)f2bf(o[0]) | ((unsigned int)f2bf(o[1]) << 16);
            unsigned int p1 = (unsigned int)f2bf(o[2]) | ((unsigned int)f2bf(o[3]) << 16);
            unsigned int p2 = (unsigned int)f2bf(o[4]) | ((unsigned int)f2bf(o[5]) << 16);
            unsigned int p3 = (unsigned int)f2bf(o[6]) | ((unsigned int)f2bf(o[7]) << 16);
            *(uint4*)(xout_bf + (size_t)node * D + cb) = make_uint4(p0, p1, p2, p3);
        }
    }
}

// ---------------------------------------------------------------------------
extern "C" void kernel_launch(void* const* d_in, const int* in_sizes, int n_in,
                              void* d_out, int out_size, void* d_ws, size_t ws_size,
                              hipStream_t stream) {
    const int*   node_types = (const int*)d_in[0];
    const int*   edge_index = (const int*)d_in[1];
    const float* emb        = (const float*)d_in[2];
    const float* projW      = (const float*)d_in[3];
    const float* projb      = (const float*)d_in[4];
    const float* projg      = (const float*)d_in[5];
    const float* projbeta   = (const float*)d_in[6];
    const float* Wl         = (const float*)d_in[7];
    const float* bl         = (const float*)d_in[8];
    const float* Wr         = (const float*)d_in[9];
    const float* br         = (const float*)d_in[10];
    const float* att        = (const float*)d_in[11];
    const float* gbias      = (const float*)d_in[12];
    const float* lng        = (const float*)d_in[13];
    const float* lnb        = (const float*)d_in[14];
    float* out = (float*)d_out;

    int n = in_sizes[0];
    int e = in_sizes[1] / 2;
    const int* srcs = edge_index;
    const int* dsts = edge_index + e;

    char* p = (char*)d_ws;
    auto carve = [&](size_t bytes) {
        char* q = p;
        p += (bytes + 255) & ~(size_t)255;
        return q;
    };
    int*   deg     = (int*)carve((size_t)n * 4);
    int*   offs    = (int*)carve((size_t)(n + 1) * 4);
    int*   cursor  = (int*)carve((size_t)n * 4);
    int*   bsum    = (int*)carve(256 * 4);
    int*   csr_src = (int*)carve((size_t)(e + n) * 4);
    unsigned short* xbuf = (unsigned short*)carve((size_t)n * D * 2);
    unsigned short* xlb  = (unsigned short*)carve((size_t)n * D * 2);
    unsigned short* xrb  = (unsigned short*)carve((size_t)n * D * 2);
    unsigned short* wt   = (unsigned short*)carve((size_t)NLAYER * 2 * D * D * 2);

    int nb = (n + 255) / 256;        // 196 for N=50000
    int nbEmbed = (n + 3) / 4;       // 12500

    // ---- fused setup: embed/proj/LN -> bf16 x ; W -> bf16 W^T ; deg=1 ----
    setup_kernel<<<nbEmbed + 512 + nb, 256, 0, stream>>>(
        node_types, emb, projW, projb, projg, projbeta, xbuf,
        Wl, Wr, wt, deg, n, nbEmbed);

    // ---- CSR build (dst-sorted, self loops included) ----
    count_deg_kernel<<<(e + 255) / 256, 256, 0, stream>>>(dsts, e, deg);
    scan_blocks_kernel<<<nb, 256, 0, stream>>>(deg, offs, bsum, n);
    scan_bsum_kernel<<<1, 256, 0, stream>>>(bsum, nb);
    add_offsets_kernel<<<(n + 255) / 256, 256, 0, stream>>>(offs, bsum, cursor, n, e + n);
    scatter_kernel<<<(e + n + 255) / 256, 256, 0, stream>>>(srcs, dsts, e, n, cursor, csr_src);

    // ---- 4 GATv2 layers ----
    for (int layer = 0; layer < NLAYER; ++layer) {
        dual_gemm_mfma_kernel<<<(n + 63) / 64, 256, 0, stream>>>(
            xbuf, wt + (size_t)layer * 2 * D * D,
            bl + (size_t)layer * D, br + (size_t)layer * D, xlb, xrb, n);
        bool last = (layer == NLAYER - 1);
        gat_agg_kernel<<<(n + 3) / 4, 256, 0, stream>>>(
            xlb, xrb, xbuf, offs, csr_src,
            att + (size_t)layer * H * CH, gbias + (size_t)layer * D,
            lng + (size_t)layer * D, lnb + (size_t)layer * D,
            last ? (unsigned short*)nullptr : xbuf, last ? out : (float*)nullptr, n);
    }
}

// Round 8
// 417.440 us; speedup vs baseline: 1.0991x; 1.0623x over previous
//
#include <hip/hip_runtime.h>
#include <hip/hip_bf16.h>
#include <math.h>

#define D      128
#define NID    16
#define H      4
#define CH     32
#define NLAYER 4
#define EPS    1e-5f
#define NEG    0.2f

typedef __attribute__((ext_vector_type(8))) short short8;
typedef __attribute__((ext_vector_type(4))) float floatx4;

__device__ __forceinline__ float2 bf2_to_f2(unsigned int u) {
    float2 r;
    unsigned int lo = u << 16;
    unsigned int hi = u & 0xffff0000u;
    r.x = __uint_as_float(lo);
    r.y = __uint_as_float(hi);
    return r;
}

__device__ __forceinline__ unsigned short f2bf(float f) {
    __hip_bfloat16 h = __float2bfloat16(f);
    return *reinterpret_cast<unsigned short*>(&h);
}

// ---------------------------------------------------------------------------
// CSR build pieces
// ---------------------------------------------------------------------------

__global__ __launch_bounds__(256) void count_deg_kernel(const int* __restrict__ dst, int e, int* deg) {
    int i = blockIdx.x * blockDim.x + threadIdx.x;
    if (i < e) atomicAdd(&deg[dst[i]], 1);
}

__global__ __launch_bounds__(256) void scan_blocks_kernel(const int* __restrict__ deg, int* __restrict__ offs,
                                                          int* __restrict__ bsum, int n) {
    __shared__ int sw[8];
    int t = threadIdx.x;
    int i = blockIdx.x * 256 + t;
    int v = (i < n) ? deg[i] : 0;
    int lane = t & 63, w = t >> 6;
    int x = v;
    #pragma unroll
    for (int off = 1; off < 64; off <<= 1) {
        int y = __shfl_up(x, off, 64);
        if (lane >= off) x += y;
    }
    if (lane == 63) sw[w] = x;
    __syncthreads();
    if (t == 0) {
        int s = 0;
        for (int k = 0; k < 4; ++k) { int tv = sw[k]; sw[k] = s; s += tv; }
        sw[4] = s;
    }
    __syncthreads();
    int excl = x - v + sw[w];
    if (i < n) offs[i] = excl;
    if (t == 255) bsum[blockIdx.x] = sw[4];
}

// fused: per-block local reduction of bsum[0..bid) + offset add + cursor init
__global__ __launch_bounds__(256) void scan_add_kernel(int* __restrict__ offs, const int* __restrict__ bsum,
                                                       int* __restrict__ cursor, int n, int nb, int total) {
    __shared__ int sw[8];
    __shared__ int sS;
    int t = threadIdx.x;
    int bid = blockIdx.x;
    int v = (t < bid && t < nb) ? bsum[t] : 0;
    int lane = t & 63, w = t >> 6;
    #pragma unroll
    for (int off = 32; off > 0; off >>= 1) v += __shfl_xor(v, off, 64);
    if (lane == 0) sw[w] = v;
    __syncthreads();
    if (t == 0) sS = sw[0] + sw[1] + sw[2] + sw[3];
    __syncthreads();
    int S = sS;
    int i = bid * 256 + t;
    if (i < n) {
        int o = offs[i] + S;
        offs[i] = o;
        cursor[i] = o;
    }
    if (i == 0) offs[n] = total;
}

__global__ __launch_bounds__(256) void scatter_kernel(const int* __restrict__ src, const int* __restrict__ dst,
                                                      int e, int n, int* cursor, int* __restrict__ csr_src) {
    int i = blockIdx.x * blockDim.x + threadIdx.x;
    if (i < e) {
        int pos = atomicAdd(&cursor[dst[i]], 1);
        csr_src[pos] = src[i];
    } else if (i < e + n) {
        int node = i - e;
        int pos = atomicAdd(&cursor[node], 1);
        csr_src[pos] = node;  // self loop
    }
}

// ---------------------------------------------------------------------------
// Fused setup: [0,nbEmbed) embed+proj+LN+ReLU -> bf16 x;
// [nbEmbed, +512) W->bf16 W^T; [then] deg init.
// ---------------------------------------------------------------------------
__global__ __launch_bounds__(256) void setup_kernel(
    const int* __restrict__ types, const float* __restrict__ emb,
    const float* __restrict__ W, const float* __restrict__ b,
    const float* __restrict__ g, const float* __restrict__ beta,
    unsigned short* __restrict__ x,
    const float* __restrict__ Wl, const float* __restrict__ Wr,
    unsigned short* __restrict__ wt, int* __restrict__ deg,
    int n, int nbEmbed) {
    __shared__ float sW[NID * D];
    __shared__ float semb[3 * NID];
    int blk = blockIdx.x;
    int t = threadIdx.x;
    if (blk < nbEmbed) {
        for (int i = t; i < NID * D; i += 256) sW[i] = W[i];
        for (int i = t; i < 3 * NID; i += 256) semb[i] = emb[i];
        __syncthreads();
        int lane = t & 63, w = t >> 6;
        int node = blk * 4 + w;
        if (node >= n) return;
        int c0 = 2 * lane;
        int ty = types[node];
        const float* e = &semb[ty * NID];
        float v0 = b[c0], v1 = b[c0 + 1];
        #pragma unroll
        for (int k = 0; k < NID; ++k) {
            float ek = e[k];
            v0 = fmaf(ek, sW[k * D + c0], v0);
            v1 = fmaf(ek, sW[k * D + c0 + 1], v1);
        }
        float s = v0 + v1, sq = v0 * v0 + v1 * v1;
        #pragma unroll
        for (int off = 1; off < 64; off <<= 1) {
            s  += __shfl_xor(s, off, 64);
            sq += __shfl_xor(sq, off, 64);
        }
        float mu  = s * (1.0f / D);
        float var = sq * (1.0f / D) - mu * mu;
        float r   = rsqrtf(var + EPS);
        v0 = fmaxf((v0 - mu) * r * g[c0]     + beta[c0],     0.0f);
        v1 = fmaxf((v1 - mu) * r * g[c0 + 1] + beta[c0 + 1], 0.0f);
        unsigned int packed = (unsigned int)f2bf(v0) | ((unsigned int)f2bf(v1) << 16);
        *(unsigned int*)(x + (size_t)node * D + c0) = packed;
    } else if (blk < nbEmbed + 512) {
        int idx = (blk - nbEmbed) * 256 + t;   // L*2*D*D = 131072
        int k    = idx & (D - 1);
        int nrow = (idx >> 7) & (D - 1);
        int s    = (idx >> 14) & 1;
        int l    = idx >> 15;
        const float* Wm = s ? Wr : Wl;
        wt[idx] = f2bf(Wm[(size_t)l * D * D + (size_t)k * D + nrow]);
    } else {
        int i = (blk - nbEmbed - 512) * 256 + t;
        if (i < n) deg[i] = 1;  // self loop
    }
}

// ---------------------------------------------------------------------------
// Dual GEMM via bf16 MFMA; bf16 in/out. All 16 B-fragments preloaded into
// registers at entry (before staging+barrier) so the K-loop is pure LDS+MFMA.
// ---------------------------------------------------------------------------
__global__ __launch_bounds__(256) void dual_gemm_mfma_kernel(
    const unsigned short* __restrict__ x, const unsigned short* __restrict__ wt,
    const float* __restrict__ bl, const float* __restrict__ br,
    unsigned short* __restrict__ xl, unsigned short* __restrict__ xr, int n) {
    __shared__ __align__(16) unsigned short sa[64 * 136];
    int t = threadIdx.x;
    int nbase = blockIdx.x * 64;
    int rows = n - nbase; if (rows > 64) rows = 64;
    int lane = t & 63, w = t >> 6;
    int L = lane & 15, q = lane >> 4;
    int s  = w >> 1;          // 0: Wl, 1: Wr
    int n0 = (w & 1) * 64;    // col strip base within this matrix
    const unsigned short* wb = wt + ((size_t)s * D + n0) * D;
    // ---- preload all B fragments (independent L2 loads, overlap staging) ----
    short8 b[4][4];           // [kk][ni]
    #pragma unroll
    for (int kk = 0; kk < 4; ++kk)
        #pragma unroll
        for (int ni = 0; ni < 4; ++ni)
            b[kk][ni] = *(const short8*)(wb + (size_t)(ni * 16 + L) * D + kk * 32 + q * 8);
    // ---- stage bf16 x -> LDS (stride 136) ----
    {
        int r   = t >> 2;
        int seg = t & 3;                 // 32 ch = 64 B each
        uint4* drow = (uint4*)(sa + r * 136 + seg * 32);
        if (r < rows) {
            const uint4* srow = (const uint4*)(x + (size_t)(nbase + r) * D + seg * 32);
            drow[0] = srow[0]; drow[1] = srow[1]; drow[2] = srow[2]; drow[3] = srow[3];
        } else {
            uint4 z = make_uint4(0, 0, 0, 0);
            drow[0] = z; drow[1] = z; drow[2] = z; drow[3] = z;
        }
    }
    __syncthreads();
    floatx4 acc[4][4];
    #pragma unroll
    for (int mi = 0; mi < 4; ++mi)
        #pragma unroll
        for (int ni = 0; ni < 4; ++ni)
            acc[mi][ni] = (floatx4){0.0f, 0.0f, 0.0f, 0.0f};
    #pragma unroll
    for (int kk = 0; kk < 4; ++kk) {
        int ko = kk * 32 + q * 8;
        short8 a[4];
        #pragma unroll
        for (int mi = 0; mi < 4; ++mi)
            a[mi] = *(const short8*)(sa + (mi * 16 + L) * 136 + ko);
        #pragma unroll
        for (int mi = 0; mi < 4; ++mi)
            #pragma unroll
            for (int ni = 0; ni < 4; ++ni)
                acc[mi][ni] = __builtin_amdgcn_mfma_f32_16x16x32_bf16(a[mi], b[kk][ni], acc[mi][ni], 0, 0, 0);
    }
    // ---- epilogue via LDS: +bias, bf16, vectorized stores ----
    const float* bias = s ? br : bl;
    #pragma unroll 1
    for (int pass = 0; pass < 2; ++pass) {
        __syncthreads();
        if (s == pass) {
            #pragma unroll
            for (int ni = 0; ni < 4; ++ni) {
                int col = n0 + ni * 16 + L;
                float bv = bias[col];
                #pragma unroll
                for (int mi = 0; mi < 4; ++mi) {
                    #pragma unroll
                    for (int r = 0; r < 4; ++r) {
                        int row = mi * 16 + q * 4 + r;
                        sa[row * 136 + col] = f2bf(acc[mi][ni][r] + bv);
                    }
                }
            }
        }
        __syncthreads();
        unsigned short* outp = pass ? xr : xl;
        #pragma unroll
        for (int c = 0; c < 4; ++c) {
            int chunk = c * 256 + t;        // 0..1023
            int row   = chunk >> 4;
            int off   = (chunk & 15) * 8;
            if (row < rows) {
                short8 v = *(const short8*)(sa + row * 136 + off);
                *(short8*)(outp + (size_t)(nbase + row) * D + off) = v;
            }
        }
    }
}

// ---------------------------------------------------------------------------
// Fused GATv2 aggregation with 1-deep gather pipeline. Wave = 1 node;
// lane = (edge slot g = lane>>4) x (channel block l = lane&15, 8 ch).
// Index prefetched 2 iters ahead, gather 1 iter ahead.
// ---------------------------------------------------------------------------
__global__ __launch_bounds__(256) void gat_agg_kernel(
    const unsigned short* __restrict__ xl, const unsigned short* __restrict__ xr,
    const unsigned short* __restrict__ xin,
    const int* __restrict__ offs, const int* __restrict__ csr_src,
    const float* __restrict__ att,
    const float* __restrict__ gbias,
    const float* __restrict__ lng, const float* __restrict__ lnb,
    unsigned short* __restrict__ xout_bf, float* __restrict__ xout_f32, int n) {
    int t = threadIdx.x;
    int lane = t & 63, w = t >> 6;
    int node = blockIdx.x * 4 + w;
    if (node >= n) return;
    int g  = lane >> 4;
    int l  = lane & 15;
    int cb = l * 8;
    float xr8[8], at8[8];
    {
        uint4 u = *(const uint4*)(xr + (size_t)node * D + cb);
        float2 a = bf2_to_f2(u.x), b = bf2_to_f2(u.y), c = bf2_to_f2(u.z), d = bf2_to_f2(u.w);
        xr8[0]=a.x; xr8[1]=a.y; xr8[2]=b.x; xr8[3]=b.y; xr8[4]=c.x; xr8[5]=c.y; xr8[6]=d.x; xr8[7]=d.y;
        float4 t0 = *(const float4*)(att + cb);
        float4 t1 = *(const float4*)(att + cb + 4);
        at8[0]=t0.x; at8[1]=t0.y; at8[2]=t0.z; at8[3]=t0.w; at8[4]=t1.x; at8[5]=t1.y; at8[6]=t1.z; at8[7]=t1.w;
    }
    float acc[8];
    #pragma unroll
    for (int i = 0; i < 8; ++i) acc[i] = 0.0f;
    float lsum = 0.0f;
    int s0 = offs[node], s1 = offs[node + 1];
    // pipeline prologue: idx(0), gather(0), idx(1)
    int j0 = s0 + g;
    bool val_c = j0 < s1;
    int src_c = csr_src[val_c ? j0 : s0];
    uint4 u_c = *(const uint4*)(xl + (size_t)src_c * D + cb);
    int j1 = j0 + 4;
    bool val_n = j1 < s1;
    int src_n = csr_src[val_n ? j1 : s0];
    for (int j = s0; j < s1; j += 4) {
        // issue gather(i+1)
        uint4 u_n = *(const uint4*)(xl + (size_t)src_n * D + cb);
        // issue idx(i+2)
        int j2 = j + 8 + g;
        bool val_2 = j2 < s1;
        int src_2 = csr_src[val_2 ? j2 : s0];
        // consume gather(i)
        float xv[8];
        {
            float2 a = bf2_to_f2(u_c.x), b = bf2_to_f2(u_c.y), c = bf2_to_f2(u_c.z), d = bf2_to_f2(u_c.w);
            xv[0]=a.x; xv[1]=a.y; xv[2]=b.x; xv[3]=b.y; xv[4]=c.x; xv[5]=c.y; xv[6]=d.x; xv[7]=d.y;
        }
        float p = 0.0f;
        #pragma unroll
        for (int i = 0; i < 8; ++i) {
            float e = xv[i] + xr8[i];
            e = fmaxf(e, NEG * e);      // leaky_relu, 0<NEG<1
            p = fmaf(at8[i], e, p);
        }
        p += __shfl_xor(p, 1, 64);      // reduce over the head's 4 lanes
        p += __shfl_xor(p, 2, 64);
        float wgt = val_c ? __expf(p) : 0.0f;
        lsum += wgt;
        #pragma unroll
        for (int i = 0; i < 8; ++i) acc[i] = fmaf(wgt, xv[i], acc[i]);
        // shift pipeline
        u_c = u_n; val_c = val_n;
        val_n = val_2; src_n = src_2;
    }
    // cross-group reduction (sum over the 4 edge slots)
    #pragma unroll
    for (int i = 0; i < 8; ++i) {
        acc[i] += __shfl_xor(acc[i], 16, 64);
        acc[i] += __shfl_xor(acc[i], 32, 64);
    }
    lsum += __shfl_xor(lsum, 16, 64);
    lsum += __shfl_xor(lsum, 32, 64);
    float inv = 1.0f / lsum;
    // bias + residual (bf16)
    float xi[8];
    {
        uint4 u = *(const uint4*)(xin + (size_t)node * D + cb);
        float2 a = bf2_to_f2(u.x), b = bf2_to_f2(u.y), c = bf2_to_f2(u.z), d = bf2_to_f2(u.w);
        xi[0]=a.x; xi[1]=a.y; xi[2]=b.x; xi[3]=b.y; xi[4]=c.x; xi[5]=c.y; xi[6]=d.x; xi[7]=d.y;
    }
    float4 gb0 = *(const float4*)(gbias + cb);
    float4 gb1 = *(const float4*)(gbias + cb + 4);
    float gb[8] = {gb0.x, gb0.y, gb0.z, gb0.w, gb1.x, gb1.y, gb1.z, gb1.w};
    float v[8];
    #pragma unroll
    for (int i = 0; i < 8; ++i) v[i] = fmaf(acc[i], inv, gb[i] + xi[i]);
    // LayerNorm over the 16 channel-block lanes
    float s = 0.0f, sq = 0.0f;
    #pragma unroll
    for (int i = 0; i < 8; ++i) { s += v[i]; sq = fmaf(v[i], v[i], sq); }
    #pragma unroll
    for (int off = 1; off < 16; off <<= 1) {
        s  += __shfl_xor(s, off, 64);
        sq += __shfl_xor(sq, off, 64);
    }
    float mu  = s * (1.0f / D);
    float var = sq * (1.0f / D) - mu * mu;
    float r   = rsqrtf(var + EPS);
    float4 lg0 = *(const float4*)(lng + cb);
    float4 lg1 = *(const float4*)(lng + cb + 4);
    float4 lb0 = *(const float4*)(lnb + cb);
    float4 lb1 = *(const float4*)(lnb + cb + 4);
    float lg[8] = {lg0.x, lg0.y, lg0.z, lg0.w, lg1.x, lg1.y, lg1.z, lg1.w};
    float lb[8] = {lb0.x, lb0.y, lb0.z, lb0.w, lb1.x, lb1.y, lb1.z, lb1.w};
    float o[8];
    #pragma unroll
    for (int i = 0; i < 8; ++i) o[i] = fmaxf((v[i] - mu) * r * lg[i] + lb[i], 0.0f);
    if (g == 0) {
        if (xout_f32) {
            *(float4*)(xout_f32 + (size_t)node * D + cb)     = make_float4(o[0], o[1], o[2], o[3]);
            *(float4*)(xout_f32 + (size_t)node * D + cb + 4) = make_float4(o[4], o[5], o[6], o[7]);
        } else {
            unsigned int p0 = (unsigned int)f2bf(o[0]) | ((unsigned int)f2bf(o[1]) << 16);
            unsigned int p1 = (unsigned int)f2bf(o[2]) | ((unsigned int)f2bf(o[3]) << 16);
            unsigned int p2 = (unsigned int)f2bf(o[4]) | ((unsigned int)f2bf(o[5]) << 16);
            unsigned int p3 = (unsigned int)f2bf(o[6]) | ((unsigned int)f2bf(o[7]) << 16);
            *(uint4*)(xout_bf + (size_t)node * D + cb) = make_uint4(p0, p1, p2, p3);
        }
    }
}

// ---------------------------------------------------------------------------
extern "C" void kernel_launch(void* const* d_in, const int* in_sizes, int n_in,
                              void* d_out, int out_size, void* d_ws, size_t ws_size,
                              hipStream_t stream) {
    const int*   node_types = (const int*)d_in[0];
    const int*   edge_index = (const int*)d_in[1];
    const float* emb        = (const float*)d_in[2];
    const float* projW      = (const float*)d_in[3];
    const float* projb      = (const float*)d_in[4];
    const float* projg      = (const float*)d_in[5];
    const float* projbeta   = (const float*)d_in[6];
    const float* Wl         = (const float*)d_in[7];
    const float* bl         = (const float*)d_in[8];
    const float* Wr         = (const float*)d_in[9];
    const float* br         = (const float*)d_in[10];
    const float* att        = (const float*)d_in[11];
    const float* gbias      = (const float*)d_in[12];
    const float* lng        = (const float*)d_in[13];
    const float* lnb        = (const float*)d_in[14];
    float* out = (float*)d_out;

    int n = in_sizes[0];
    int e = in_sizes[1] / 2;
    const int* srcs = edge_index;
    const int* dsts = edge_index + e;

    char* p = (char*)d_ws;
    auto carve = [&](size_t bytes) {
        char* q = p;
        p += (bytes + 255) & ~(size_t)255;
        return q;
    };
    int*   deg     = (int*)carve((size_t)n * 4);
    int*   offs    = (int*)carve((size_t)(n + 1) * 4);
    int*   cursor  = (int*)carve((size_t)n * 4);
    int*   bsum    = (int*)carve(256 * 4);
    int*   csr_src = (int*)carve((size_t)(e + n) * 4);
    unsigned short* xbuf = (unsigned short*)carve((size_t)n * D * 2);
    unsigned short* xlb  = (unsigned short*)carve((size_t)n * D * 2);
    unsigned short* xrb  = (unsigned short*)carve((size_t)n * D * 2);
    unsigned short* wt   = (unsigned short*)carve((size_t)NLAYER * 2 * D * D * 2);

    int nb = (n + 255) / 256;        // 196 for N=50000
    int nbEmbed = (n + 3) / 4;       // 12500

    // ---- fused setup: embed/proj/LN -> bf16 x ; W -> bf16 W^T ; deg=1 ----
    setup_kernel<<<nbEmbed + 512 + nb, 256, 0, stream>>>(
        node_types, emb, projW, projb, projg, projbeta, xbuf,
        Wl, Wr, wt, deg, n, nbEmbed);

    // ---- CSR build (dst-sorted, self loops included) ----
    count_deg_kernel<<<(e + 255) / 256, 256, 0, stream>>>(dsts, e, deg);
    scan_blocks_kernel<<<nb, 256, 0, stream>>>(deg, offs, bsum, n);
    scan_add_kernel<<<nb, 256, 0, stream>>>(offs, bsum, cursor, n, nb, e + n);
    scatter_kernel<<<(e + n + 255) / 256, 256, 0, stream>>>(srcs, dsts, e, n, cursor, csr_src);

    // ---- 4 GATv2 layers ----
    for (int layer = 0; layer < NLAYER; ++layer) {
        dual_gemm_mfma_kernel<<<(n + 63) / 64, 256, 0, stream>>>(
            xbuf, wt + (size_t)layer * 2 * D * D,
            bl + (size_t)layer * D, br + (size_t)layer * D, xlb, xrb, n);
        bool last = (layer == NLAYER - 1);
        gat_agg_kernel<<<(n + 3) / 4, 256, 0, stream>>>(
            xlb, xrb, xbuf, offs, csr_src,
            att + (size_t)layer * H * CH, gbias + (size_t)layer * D,
            lng + (size_t)layer * D, lnb + (size_t)layer * D,
            last ? (unsigned short*)nullptr : xbuf, last ? out : (float*)nullptr, n);
    }
}